// Round 2
// baseline (434.195 us; speedup 1.0000x reference)
//
#include <hip/hip_runtime.h>
#include <stdint.h>

// Problem constants (setup_inputs: T=4096, B=4096, C=2)
#define T_STEPS 4096
#define B_SIZE  4096
#define NWORDS  (T_STEPS / 32)   // 128 packed words of 32 timesteps each
#define B2      (B_SIZE / 2)
#define B4      (B_SIZE / 4)

// Reference step (per batch element b):
//   cur_exc = x0*w00 + x1*w01
//   inh     = 0.6*inh + x0 ; cur_inh = w_inh*inh ; cur = cur_exc + cur_inh
//   reset   = (mem > 1) ; mem = (0.9*mem + cur) - reset ; spk = (mem > 1)
// Outputs (flat, in order): spk_rec, exc_rec, inh_rec, mem_rec, each (T,B).

__device__ __forceinline__ float bitf(uint32_t w, int k) {
    return (float)((w >> k) & 1u);
}

// ---------------------------------------------------------------------------
// K0: pack spike bits. x is (T,B,2) f32, values exactly 0.0 or 1.0.
// Thread handles 2 consecutive b (one float4 = {x0(b),x1(b),x0(b+1),x1(b+1)}).
// ---------------------------------------------------------------------------
__global__ __launch_bounds__(256) void k_pack(const float4* __restrict__ x,
                                              uint2* __restrict__ p0,
                                              uint2* __restrict__ p1) {
    uint32_t gid = blockIdx.x * 256u + threadIdx.x;
    uint32_t i  = gid >> 11;            // word index   (B2 == 2048)
    uint32_t bp = gid & (B2 - 1);       // b-pair index (coalesced across lanes)
    const float4* xp = x + (size_t)i * 32u * B2 + bp;
    uint32_t e0 = 0u, e1 = 0u, o0 = 0u, o1 = 0u;
#pragma unroll
    for (int k = 0; k < 32; ++k) {
        float4 v = xp[(size_t)k * B2];
        e0 |= ((uint32_t)(v.x != 0.0f)) << k;   // b even, ch0
        e1 |= ((uint32_t)(v.y != 0.0f)) << k;   // b even, ch1
        o0 |= ((uint32_t)(v.z != 0.0f)) << k;   // b odd,  ch0
        o1 |= ((uint32_t)(v.w != 0.0f)) << k;   // b odd,  ch1
    }
    p0[(size_t)i * B2 + bp] = make_uint2(e0, o0);
    p1[(size_t)i * B2 + bp] = make_uint2(e1, o1);
}

// ---------------------------------------------------------------------------
// K1: serial scan over T per batch element, from packed bits (4 MiB, cached).
// Writes exact state checkpoints (mem, inh) BEFORE each 32-step word.
// Chain per step: mul(0.9,mem) -> fma -> sub  (cmp/cndmask off-chain).
// ---------------------------------------------------------------------------
__global__ __launch_bounds__(256) void k_scan(const uint32_t* __restrict__ p0,
                                              const uint32_t* __restrict__ p1,
                                              const float* __restrict__ w_exc,
                                              const float* __restrict__ w_inh_p,
                                              float* __restrict__ mem_ck,
                                              float* __restrict__ inh_ck) {
    int b = blockIdx.x * 256 + threadIdx.x;
    const float w00 = w_exc[0], w01 = w_exc[1], winh = w_inh_p[0];
    float mem = 0.0f, inh = 0.0f;

    if (w00 == 0.0f && winh == 0.0f) {
        // Fast path: cur = w01*x1 exactly (x1*w01 exact for x1 in {0,1};
        // fma(x1,w01,m1) == round(m1 + cur), matching reference rounding).
        uint32_t w1 = p1[b];
        for (int i = 0; i < NWORDS; ++i) {
            uint32_t w1n = (i + 1 < NWORDS) ? p1[(size_t)(i + 1) * B_SIZE + b] : 0u;
            mem_ck[(size_t)i * B_SIZE + b] = mem;
#pragma unroll
            for (int k = 0; k < 32; ++k) {
                float x1f = bitf(w1, k);
                float r   = (mem > 1.0f) ? 1.0f : 0.0f;   // off the critical chain
                float m1  = __fmul_rn(0.9f, mem);
                float m2  = __fmaf_rn(x1f, w01, m1);
                mem       = __fsub_rn(m2, r);
            }
            w1 = w1n;
        }
    } else {
        uint32_t w0 = p0[b], w1 = p1[b];
        for (int i = 0; i < NWORDS; ++i) {
            uint32_t w0n = (i + 1 < NWORDS) ? p0[(size_t)(i + 1) * B_SIZE + b] : 0u;
            uint32_t w1n = (i + 1 < NWORDS) ? p1[(size_t)(i + 1) * B_SIZE + b] : 0u;
            mem_ck[(size_t)i * B_SIZE + b] = mem;
            inh_ck[(size_t)i * B_SIZE + b] = inh;
#pragma unroll
            for (int k = 0; k < 32; ++k) {
                float x0f = bitf(w0, k);
                float x1f = bitf(w1, k);
                float exc = __fadd_rn(__fmul_rn(x0f, w00), __fmul_rn(x1f, w01));
                inh       = __fadd_rn(__fmul_rn(0.6f, inh), x0f);
                float ci  = __fmul_rn(winh, inh);
                float cur = __fadd_rn(exc, ci);
                float r   = (mem > 1.0f) ? 1.0f : 0.0f;
                float m1  = __fmul_rn(0.9f, mem);
                float m2  = __fadd_rn(m1, cur);
                mem       = __fsub_rn(m2, r);
            }
            w0 = w0n; w1 = w1n;
        }
    }
}

// ---------------------------------------------------------------------------
// K2: parallel replay. One thread per (32-step chunk, 4 consecutive b):
// 4 independent membrane chains (ILP) + dwordx4 stores on all 4 streams.
// ---------------------------------------------------------------------------
__global__ __launch_bounds__(256) void k_replay(const uint32_t* __restrict__ p0,
                                                const uint32_t* __restrict__ p1,
                                                const float* __restrict__ w_exc,
                                                const float* __restrict__ w_inh_p,
                                                const float* __restrict__ mem_ck,
                                                const float* __restrict__ inh_ck,
                                                float* __restrict__ out) {
    uint32_t gid = blockIdx.x * 256u + threadIdx.x;
    uint32_t i = gid >> 10;             // chunk index   (B4 == 1024)
    uint32_t q = gid & (B4 - 1);        // b-quad index  (b = 4q, coalesced)
    float4* __restrict__ spk4 = (float4*)out;
    float4* __restrict__ exc4 = (float4*)(out + (size_t)T_STEPS * B_SIZE);
    float4* __restrict__ inh4 = (float4*)(out + 2 * (size_t)T_STEPS * B_SIZE);
    float4* __restrict__ mem4 = (float4*)(out + 3 * (size_t)T_STEPS * B_SIZE);
    const float w00 = w_exc[0], w01 = w_exc[1], winh = w_inh_p[0];

    float4 mem = ((const float4*)mem_ck)[(size_t)i * B4 + q];
    uint4  w1q = ((const uint4*)p1)[(size_t)i * B4 + q];
    size_t base = (size_t)i * 32u * B4 + q;

    if (w00 == 0.0f && winh == 0.0f) {
        const float4 z4 = make_float4(0.0f, 0.0f, 0.0f, 0.0f);
#pragma unroll
        for (int k = 0; k < 32; ++k) {
            float4 x1f = make_float4(bitf(w1q.x, k), bitf(w1q.y, k),
                                     bitf(w1q.z, k), bitf(w1q.w, k));
            float4 exc, spk;
            {
                float r = (mem.x > 1.0f) ? 1.0f : 0.0f;
                exc.x = __fmul_rn(x1f.x, w01);
                mem.x = __fsub_rn(__fmaf_rn(x1f.x, w01, __fmul_rn(0.9f, mem.x)), r);
                spk.x = (mem.x > 1.0f) ? 1.0f : 0.0f;
            }
            {
                float r = (mem.y > 1.0f) ? 1.0f : 0.0f;
                exc.y = __fmul_rn(x1f.y, w01);
                mem.y = __fsub_rn(__fmaf_rn(x1f.y, w01, __fmul_rn(0.9f, mem.y)), r);
                spk.y = (mem.y > 1.0f) ? 1.0f : 0.0f;
            }
            {
                float r = (mem.z > 1.0f) ? 1.0f : 0.0f;
                exc.z = __fmul_rn(x1f.z, w01);
                mem.z = __fsub_rn(__fmaf_rn(x1f.z, w01, __fmul_rn(0.9f, mem.z)), r);
                spk.z = (mem.z > 1.0f) ? 1.0f : 0.0f;
            }
            {
                float r = (mem.w > 1.0f) ? 1.0f : 0.0f;
                exc.w = __fmul_rn(x1f.w, w01);
                mem.w = __fsub_rn(__fmaf_rn(x1f.w, w01, __fmul_rn(0.9f, mem.w)), r);
                spk.w = (mem.w > 1.0f) ? 1.0f : 0.0f;
            }
            size_t idx = base + (size_t)k * B4;
            spk4[idx] = spk;
            exc4[idx] = exc;
            inh4[idx] = z4;       // w_inh * inh == +0.0
            mem4[idx] = mem;
        }
    } else {
        float4 inh = ((const float4*)inh_ck)[(size_t)i * B4 + q];
        uint4  w0q = ((const uint4*)p0)[(size_t)i * B4 + q];
#pragma unroll
        for (int k = 0; k < 32; ++k) {
            float4 excv, civ, spkv;
#define STEP(C)                                                              \
            {                                                                \
                float x0f = bitf(w0q.C, k);                                  \
                float x1f = bitf(w1q.C, k);                                  \
                float exc = __fadd_rn(__fmul_rn(x0f, w00), __fmul_rn(x1f, w01)); \
                inh.C     = __fadd_rn(__fmul_rn(0.6f, inh.C), x0f);          \
                float ci  = __fmul_rn(winh, inh.C);                          \
                float cur = __fadd_rn(exc, ci);                              \
                float r   = (mem.C > 1.0f) ? 1.0f : 0.0f;                    \
                mem.C     = __fsub_rn(__fadd_rn(__fmul_rn(0.9f, mem.C), cur), r); \
                excv.C = exc; civ.C = ci;                                    \
                spkv.C = (mem.C > 1.0f) ? 1.0f : 0.0f;                       \
            }
            STEP(x) STEP(y) STEP(z) STEP(w)
#undef STEP
            size_t idx = base + (size_t)k * B4;
            spk4[idx] = spkv;
            exc4[idx] = excv;
            inh4[idx] = civ;
            mem4[idx] = mem;
        }
    }
}

// ---------------------------------------------------------------------------
// Fallback: fully serial per batch element (used only if ws too small).
// ---------------------------------------------------------------------------
__global__ __launch_bounds__(256) void k_naive(const float2* __restrict__ x,
                                               const float* __restrict__ w_exc,
                                               const float* __restrict__ w_inh_p,
                                               float* __restrict__ out) {
    int b = blockIdx.x * 256 + threadIdx.x;
    const float w00 = w_exc[0], w01 = w_exc[1], winh = w_inh_p[0];
    float* __restrict__ spk_o = out;
    float* __restrict__ exc_o = out + (size_t)T_STEPS * B_SIZE;
    float* __restrict__ inh_o = out + 2 * (size_t)T_STEPS * B_SIZE;
    float* __restrict__ mem_o = out + 3 * (size_t)T_STEPS * B_SIZE;
    float mem = 0.0f, inh = 0.0f;
    for (int t = 0; t < T_STEPS; ++t) {
        float2 v = x[(size_t)t * B_SIZE + b];
        float exc = __fadd_rn(__fmul_rn(v.x, w00), __fmul_rn(v.y, w01));
        inh       = __fadd_rn(__fmul_rn(0.6f, inh), v.x);
        float ci  = __fmul_rn(winh, inh);
        float cur = __fadd_rn(exc, ci);
        float r   = (mem > 1.0f) ? 1.0f : 0.0f;
        float m1  = __fmul_rn(0.9f, mem);
        mem       = __fsub_rn(__fadd_rn(m1, cur), r);
        float spk = (mem > 1.0f) ? 1.0f : 0.0f;
        size_t idx = (size_t)t * B_SIZE + b;
        spk_o[idx] = spk; exc_o[idx] = exc; inh_o[idx] = ci; mem_o[idx] = mem;
    }
}

extern "C" void kernel_launch(void* const* d_in, const int* in_sizes, int n_in,
                              void* d_out, int out_size, void* d_ws, size_t ws_size,
                              hipStream_t stream) {
    const float4* x4     = (const float4*)d_in[0];  // (T,B,2) f32 as float4 pairs
    const float*  w_exc  = (const float*)d_in[1];   // (1,2) f32
    const float*  w_inh  = (const float*)d_in[2];   // scalar f32
    float* out = (float*)d_out;

    const size_t nw = (size_t)NWORDS * B_SIZE;
    const size_t need = nw * (sizeof(uint32_t) * 2 + sizeof(float) * 2); // 8 MiB

    if (ws_size >= need) {
        uint32_t* p0     = (uint32_t*)d_ws;
        uint32_t* p1     = p0 + nw;
        float*    mem_ck = (float*)(p1 + nw);
        float*    inh_ck = mem_ck + nw;

        // K0: pack — NWORDS * B/2 threads, float4 loads / uint2 stores
        k_pack<<<(NWORDS * B2) / 256, 256, 0, stream>>>(x4, (uint2*)p0, (uint2*)p1);
        // K1: serial checkpoint scan — B threads
        k_scan<<<B_SIZE / 256, 256, 0, stream>>>(p0, p1, w_exc, w_inh, mem_ck, inh_ck);
        // K2: parallel replay — NWORDS * B/4 threads, dwordx4 everything
        k_replay<<<(NWORDS * B4) / 256, 256, 0, stream>>>(p0, p1, w_exc, w_inh,
                                                          mem_ck, inh_ck, out);
    } else {
        k_naive<<<B_SIZE / 256, 256, 0, stream>>>((const float2*)d_in[0], w_exc, w_inh, out);
    }
}

// Round 4
// 432.357 us; speedup vs baseline: 1.0043x; 1.0043x over previous
//
#include <hip/hip_runtime.h>
#include <stdint.h>

// Problem constants (setup_inputs: T=4096, B=4096, C=2)
#define T_STEPS 4096
#define B_SIZE  4096
#define NWORDS  (T_STEPS / 32)   // 128 packed words of 32 timesteps each
#define B2      (B_SIZE / 2)
#define B4      (B_SIZE / 4)

// Clang native vector types: required by __builtin_nontemporal_{load,store}
// (HIP_vector_type float4/uint4 are rejected by the builtin).
typedef float    f32x4 __attribute__((ext_vector_type(4)));
typedef uint32_t u32x4 __attribute__((ext_vector_type(4)));
typedef uint32_t u32x2 __attribute__((ext_vector_type(2)));

// Reference step (per batch element b):
//   cur_exc = x0*w00 + x1*w01
//   inh     = 0.6*inh + x0 ; cur_inh = w_inh*inh ; cur = cur_exc + cur_inh
//   reset   = (mem > 1) ; mem = (0.9*mem + cur) - reset ; spk = (mem > 1)
// Outputs (flat, in order): spk_rec, exc_rec, inh_rec, mem_rec, each (T,B).

__device__ __forceinline__ float bitf(uint32_t w, int k) {
    return (float)((w >> k) & 1u);
}

// ---------------------------------------------------------------------------
// K0: pack spike bits. x is (T,B,2) f32, values exactly 0.0 or 1.0.
// Thread handles 2 consecutive b (one f32x4 = {x0(b),x1(b),x0(b+1),x1(b+1)}).
// Input is read-once: nontemporal loads keep 128 MiB out of L2.
// ---------------------------------------------------------------------------
__global__ __launch_bounds__(256) void k_pack(const f32x4* __restrict__ x,
                                              u32x2* __restrict__ p0,
                                              u32x2* __restrict__ p1) {
    uint32_t gid = blockIdx.x * 256u + threadIdx.x;
    uint32_t i  = gid >> 11;            // word index   (B2 == 2048)
    uint32_t bp = gid & (B2 - 1);       // b-pair index (coalesced across lanes)
    const f32x4* xp = x + (size_t)i * 32u * B2 + bp;
    uint32_t e0 = 0u, e1 = 0u, o0 = 0u, o1 = 0u;
#pragma unroll
    for (int k = 0; k < 32; ++k) {
        f32x4 v = __builtin_nontemporal_load(xp + (size_t)k * B2);
        e0 |= ((uint32_t)(v.x != 0.0f)) << k;   // b even, ch0
        e1 |= ((uint32_t)(v.y != 0.0f)) << k;   // b even, ch1
        o0 |= ((uint32_t)(v.z != 0.0f)) << k;   // b odd,  ch0
        o1 |= ((uint32_t)(v.w != 0.0f)) << k;   // b odd,  ch1
    }
    // p0/p1 ARE re-read (scan+replay): normal stores so they stay in L2.
    u32x2 s0; s0.x = e0; s0.y = o0;
    u32x2 s1; s1.x = e1; s1.y = o1;
    p0[(size_t)i * B2 + bp] = s0;
    p1[(size_t)i * B2 + bp] = s1;
}

// ---------------------------------------------------------------------------
// K1: serial scan over T per batch element, from packed bits.
// One wave per block (64 blocks x 64 threads) -> each wave gets a SIMD to
// itself for max issue rate on the serial chain. Prefetch 4 words ahead:
// shadow = 128 steps x ~12cy ~= 1500 cy > 900 cy HBM-miss latency.
// Writes exact state checkpoints (mem, inh) BEFORE each 32-step word.
// Chain per step: mul(0.9,mem) -> fma -> sub  (cmp/cndmask off-chain).
// ---------------------------------------------------------------------------
__global__ __launch_bounds__(64) void k_scan(const uint32_t* __restrict__ p0,
                                             const uint32_t* __restrict__ p1,
                                             const float* __restrict__ w_exc,
                                             const float* __restrict__ w_inh_p,
                                             float* __restrict__ mem_ck,
                                             float* __restrict__ inh_ck) {
    int b = blockIdx.x * 64 + threadIdx.x;
    const float w00 = w_exc[0], w01 = w_exc[1], winh = w_inh_p[0];
    float mem = 0.0f, inh = 0.0f;

    if (w00 == 0.0f && winh == 0.0f) {
        // Fast path: cur = w01*x1 exactly (x1*w01 exact for x1 in {0,1};
        // fma(x1,w01,m1) == round(m1 + cur), matching reference rounding).
        uint32_t c0 = p1[b];
        uint32_t c1 = p1[(size_t)1 * B_SIZE + b];
        uint32_t c2 = p1[(size_t)2 * B_SIZE + b];
        uint32_t c3 = p1[(size_t)3 * B_SIZE + b];
        for (int i = 0; i < NWORDS; i += 4) {
            uint32_t n0 = 0u, n1 = 0u, n2 = 0u, n3 = 0u;
            if (i + 4 < NWORDS) {           // issue 4 loads, consumed next chunk
                n0 = p1[(size_t)(i + 4) * B_SIZE + b];
                n1 = p1[(size_t)(i + 5) * B_SIZE + b];
                n2 = p1[(size_t)(i + 6) * B_SIZE + b];
                n3 = p1[(size_t)(i + 7) * B_SIZE + b];
            }
            uint32_t ws[4] = {c0, c1, c2, c3};
#pragma unroll
            for (int j = 0; j < 4; ++j) {
                mem_ck[(size_t)(i + j) * B_SIZE + b] = mem;
                uint32_t w1 = ws[j];
#pragma unroll
                for (int k = 0; k < 32; ++k) {
                    float x1f = bitf(w1, k);
                    float r   = (mem > 1.0f) ? 1.0f : 0.0f;  // off the mul->fma chain
                    float m1  = __fmul_rn(0.9f, mem);
                    float m2  = __fmaf_rn(x1f, w01, m1);
                    mem       = __fsub_rn(m2, r);
                }
            }
            c0 = n0; c1 = n1; c2 = n2; c3 = n3;
        }
    } else {
        uint32_t a0 = p0[b];
        uint32_t a1 = p0[(size_t)1 * B_SIZE + b];
        uint32_t a2 = p0[(size_t)2 * B_SIZE + b];
        uint32_t a3 = p0[(size_t)3 * B_SIZE + b];
        uint32_t c0 = p1[b];
        uint32_t c1 = p1[(size_t)1 * B_SIZE + b];
        uint32_t c2 = p1[(size_t)2 * B_SIZE + b];
        uint32_t c3 = p1[(size_t)3 * B_SIZE + b];
        for (int i = 0; i < NWORDS; i += 4) {
            uint32_t m0 = 0u, m1_ = 0u, m2_ = 0u, m3 = 0u;
            uint32_t n0 = 0u, n1 = 0u, n2 = 0u, n3 = 0u;
            if (i + 4 < NWORDS) {
                m0 = p0[(size_t)(i + 4) * B_SIZE + b];
                m1_ = p0[(size_t)(i + 5) * B_SIZE + b];
                m2_ = p0[(size_t)(i + 6) * B_SIZE + b];
                m3 = p0[(size_t)(i + 7) * B_SIZE + b];
                n0 = p1[(size_t)(i + 4) * B_SIZE + b];
                n1 = p1[(size_t)(i + 5) * B_SIZE + b];
                n2 = p1[(size_t)(i + 6) * B_SIZE + b];
                n3 = p1[(size_t)(i + 7) * B_SIZE + b];
            }
            uint32_t wa[4] = {a0, a1, a2, a3};
            uint32_t wc[4] = {c0, c1, c2, c3};
#pragma unroll
            for (int j = 0; j < 4; ++j) {
                mem_ck[(size_t)(i + j) * B_SIZE + b] = mem;
                inh_ck[(size_t)(i + j) * B_SIZE + b] = inh;
                uint32_t w0 = wa[j], w1 = wc[j];
#pragma unroll
                for (int k = 0; k < 32; ++k) {
                    float x0f = bitf(w0, k);
                    float x1f = bitf(w1, k);
                    float exc = __fadd_rn(__fmul_rn(x0f, w00), __fmul_rn(x1f, w01));
                    inh       = __fadd_rn(__fmul_rn(0.6f, inh), x0f);
                    float ci  = __fmul_rn(winh, inh);
                    float cur = __fadd_rn(exc, ci);
                    float r   = (mem > 1.0f) ? 1.0f : 0.0f;
                    float mm1 = __fmul_rn(0.9f, mem);
                    float mm2 = __fadd_rn(mm1, cur);
                    mem       = __fsub_rn(mm2, r);
                }
            }
            a0 = m0; a1 = m1_; a2 = m2_; a3 = m3;
            c0 = n0; c1 = n1; c2 = n2; c3 = n3;
        }
    }
}

// ---------------------------------------------------------------------------
// K2: parallel replay. One thread per (32-step chunk, 4 consecutive b):
// 4 independent membrane chains (ILP); ALL output stores nontemporal
// (streaming 256 MiB, zero reuse -> bypass L2).
// ---------------------------------------------------------------------------
__global__ __launch_bounds__(256) void k_replay(const uint32_t* __restrict__ p0,
                                                const uint32_t* __restrict__ p1,
                                                const float* __restrict__ w_exc,
                                                const float* __restrict__ w_inh_p,
                                                const float* __restrict__ mem_ck,
                                                const float* __restrict__ inh_ck,
                                                float* __restrict__ out) {
    uint32_t gid = blockIdx.x * 256u + threadIdx.x;
    uint32_t i = gid >> 10;             // chunk index   (B4 == 1024)
    uint32_t q = gid & (B4 - 1);        // b-quad index  (b = 4q, coalesced)
    f32x4* __restrict__ spk4 = (f32x4*)out;
    f32x4* __restrict__ exc4 = (f32x4*)(out + (size_t)T_STEPS * B_SIZE);
    f32x4* __restrict__ inh4 = (f32x4*)(out + 2 * (size_t)T_STEPS * B_SIZE);
    f32x4* __restrict__ mem4 = (f32x4*)(out + 3 * (size_t)T_STEPS * B_SIZE);
    const float w00 = w_exc[0], w01 = w_exc[1], winh = w_inh_p[0];

    f32x4 mem = ((const f32x4*)mem_ck)[(size_t)i * B4 + q];
    u32x4 w1q = ((const u32x4*)p1)[(size_t)i * B4 + q];
    size_t base = (size_t)i * 32u * B4 + q;

    if (w00 == 0.0f && winh == 0.0f) {
        f32x4 z4; z4.x = 0.0f; z4.y = 0.0f; z4.z = 0.0f; z4.w = 0.0f;
#pragma unroll
        for (int k = 0; k < 32; ++k) {
            f32x4 exc, spk;
#define STEPF(C, W)                                                          \
            {                                                                \
                float x1f = bitf(W, k);                                      \
                float r   = (mem.C > 1.0f) ? 1.0f : 0.0f;                    \
                exc.C = __fmul_rn(x1f, w01);                                 \
                mem.C = __fsub_rn(__fmaf_rn(x1f, w01, __fmul_rn(0.9f, mem.C)), r); \
                spk.C = (mem.C > 1.0f) ? 1.0f : 0.0f;                        \
            }
            STEPF(x, w1q.x) STEPF(y, w1q.y) STEPF(z, w1q.z) STEPF(w, w1q.w)
#undef STEPF
            size_t idx = base + (size_t)k * B4;
            __builtin_nontemporal_store(spk, spk4 + idx);
            __builtin_nontemporal_store(exc, exc4 + idx);
            __builtin_nontemporal_store(z4,  inh4 + idx);   // w_inh*inh == +0.0
            __builtin_nontemporal_store(mem, mem4 + idx);
        }
    } else {
        f32x4 inh = ((const f32x4*)inh_ck)[(size_t)i * B4 + q];
        u32x4 w0q = ((const u32x4*)p0)[(size_t)i * B4 + q];
#pragma unroll
        for (int k = 0; k < 32; ++k) {
            f32x4 excv, civ, spkv;
#define STEP(C)                                                              \
            {                                                                \
                float x0f = bitf(w0q.C, k);                                  \
                float x1f = bitf(w1q.C, k);                                  \
                float exc = __fadd_rn(__fmul_rn(x0f, w00), __fmul_rn(x1f, w01)); \
                inh.C     = __fadd_rn(__fmul_rn(0.6f, inh.C), x0f);          \
                float ci  = __fmul_rn(winh, inh.C);                          \
                float cur = __fadd_rn(exc, ci);                              \
                float r   = (mem.C > 1.0f) ? 1.0f : 0.0f;                    \
                mem.C     = __fsub_rn(__fadd_rn(__fmul_rn(0.9f, mem.C), cur), r); \
                excv.C = exc; civ.C = ci;                                    \
                spkv.C = (mem.C > 1.0f) ? 1.0f : 0.0f;                       \
            }
            STEP(x) STEP(y) STEP(z) STEP(w)
#undef STEP
            size_t idx = base + (size_t)k * B4;
            __builtin_nontemporal_store(spkv, spk4 + idx);
            __builtin_nontemporal_store(excv, exc4 + idx);
            __builtin_nontemporal_store(civ,  inh4 + idx);
            __builtin_nontemporal_store(mem,  mem4 + idx);
        }
    }
}

// ---------------------------------------------------------------------------
// Fallback: fully serial per batch element (used only if ws too small).
// ---------------------------------------------------------------------------
__global__ __launch_bounds__(256) void k_naive(const float2* __restrict__ x,
                                               const float* __restrict__ w_exc,
                                               const float* __restrict__ w_inh_p,
                                               float* __restrict__ out) {
    int b = blockIdx.x * 256 + threadIdx.x;
    const float w00 = w_exc[0], w01 = w_exc[1], winh = w_inh_p[0];
    float* __restrict__ spk_o = out;
    float* __restrict__ exc_o = out + (size_t)T_STEPS * B_SIZE;
    float* __restrict__ inh_o = out + 2 * (size_t)T_STEPS * B_SIZE;
    float* __restrict__ mem_o = out + 3 * (size_t)T_STEPS * B_SIZE;
    float mem = 0.0f, inh = 0.0f;
    for (int t = 0; t < T_STEPS; ++t) {
        float2 v = x[(size_t)t * B_SIZE + b];
        float exc = __fadd_rn(__fmul_rn(v.x, w00), __fmul_rn(v.y, w01));
        inh       = __fadd_rn(__fmul_rn(0.6f, inh), v.x);
        float ci  = __fmul_rn(winh, inh);
        float cur = __fadd_rn(exc, ci);
        float r   = (mem > 1.0f) ? 1.0f : 0.0f;
        float m1  = __fmul_rn(0.9f, mem);
        mem       = __fsub_rn(__fadd_rn(m1, cur), r);
        float spk = (mem > 1.0f) ? 1.0f : 0.0f;
        size_t idx = (size_t)t * B_SIZE + b;
        spk_o[idx] = spk; exc_o[idx] = exc; inh_o[idx] = ci; mem_o[idx] = mem;
    }
}

extern "C" void kernel_launch(void* const* d_in, const int* in_sizes, int n_in,
                              void* d_out, int out_size, void* d_ws, size_t ws_size,
                              hipStream_t stream) {
    const f32x4*  x4     = (const f32x4*)d_in[0];   // (T,B,2) f32 as float4 pairs
    const float*  w_exc  = (const float*)d_in[1];   // (1,2) f32
    const float*  w_inh  = (const float*)d_in[2];   // scalar f32
    float* out = (float*)d_out;

    const size_t nw = (size_t)NWORDS * B_SIZE;
    const size_t need = nw * (sizeof(uint32_t) * 2 + sizeof(float) * 2); // 8 MiB

    if (ws_size >= need) {
        uint32_t* p0     = (uint32_t*)d_ws;
        uint32_t* p1     = p0 + nw;
        float*    mem_ck = (float*)(p1 + nw);
        float*    inh_ck = mem_ck + nw;

        // K0: pack — NWORDS * B/2 threads, f32x4 nt-loads / u32x2 stores
        k_pack<<<(NWORDS * B2) / 256, 256, 0, stream>>>(x4, (u32x2*)p0, (u32x2*)p1);
        // K1: serial checkpoint scan — 64 blocks x 64 threads (1 wave/block)
        k_scan<<<B_SIZE / 64, 64, 0, stream>>>(p0, p1, w_exc, w_inh, mem_ck, inh_ck);
        // K2: parallel replay — NWORDS * B/4 threads, dwordx4 nt-stores
        k_replay<<<(NWORDS * B4) / 256, 256, 0, stream>>>(p0, p1, w_exc, w_inh,
                                                          mem_ck, inh_ck, out);
    } else {
        k_naive<<<B_SIZE / 256, 256, 0, stream>>>((const float2*)d_in[0], w_exc, w_inh, out);
    }
}